// Round 5
// baseline (1635.788 us; speedup 1.0000x reference)
//
#include <hip/hip_runtime.h>
#include <hip/hip_bf16.h>

// Elman RNN: B=256, T=512, H=1024, O=256 (fp32 in/out), MI355X gfx950.
// Round 5: 128 WGs = 16 batch-groups x 8 members, 512 threads (8 waves =
// 2 col-groups x 4 k-quarters). Each WG holds a 1024x128 W_ih slice in
// registers (A = W^T bf16 frags, 128 VGPR/lane). Per step: stage group's
// 16x1024 h slice (coalesced sc0|sc1 bypass loads) into swizzled LDS once;
// each wave computes 4 m-tiles (64 cols) over its 256-k quarter (one B
// granule feeds 4 MFMAs); 3-way k-partial exchange through LDS; owner wave
// does tanh + one 8B write-through store of its 4 contiguous h cols.
// Coherence: sc0|sc1 write-through stores + bypass loads at the MALL; 8
// per-group flags (relaxed agent atomics). No L2 flush/inv fences.

#define Bsz 256
#define Tn  512
#define Hn  1024
#define On  256

typedef __attribute__((ext_vector_type(8))) short bf16x8;  // 8 bf16 = 4 VGPR
typedef __attribute__((ext_vector_type(4))) float f32x4;
typedef __attribute__((ext_vector_type(4))) int   i32x4;
typedef __attribute__((ext_vector_type(2))) int   i32x2;

__device__ __forceinline__ short f2bf(float f) {
    union { float f; unsigned u; } v; v.f = f;
    unsigned r = v.u + 0x7FFFu + ((v.u >> 16) & 1u);   // RNE
    return (short)(r >> 16);
}

__device__ __forceinline__ bf16x8 as_bf16x8(i32x4 v) {
    union { i32x4 i; bf16x8 b; } u; u.i = v; return u.b;
}

// tanh = (e^{2x}-1)/(e^{2x}+1), e^{2x} = 2^{x*2log2e}; clamp keeps exp finite.
// |err| ~1e-6 << bf16 rounding. 3 VALU + 1 transcendental vs ocml's ~20.
__device__ __forceinline__ float fast_tanh(float x) {
    float xc = fminf(fmaxf(x, -9.f), 9.f);
    float e  = __builtin_amdgcn_exp2f(xc * 2.8853900817779268f);
    return (e - 1.f) * __builtin_amdgcn_rcpf(e + 1.f);
}

// Stage this group's 16x1024 bf16 h slice into LDS (wave w: rows 2w,2w+1).
// Each load instr: 64 lanes x 16B = one contiguous 1024B span (8 full lines).
// LDS: granule g of row r at 16B-index r*128 + (g ^ (r&7)) (conflict-free
// permutation per instr; matches MFMA B-frag read swizzle).
__device__ __forceinline__ void stage_h(const short* __restrict__ hsrc,
                                        short* __restrict__ htile,
                                        int row0, int w, int lane) {
    const short* gp = hsrc + (size_t)(row0 + 2 * w) * Hn + lane * 8;
    i32x4 t0, t1, t2, t3;
    asm volatile(
        "global_load_dwordx4 %0, %4, off sc0 sc1\n\t"
        "global_load_dwordx4 %1, %4, off offset:1024 sc0 sc1\n\t"
        "global_load_dwordx4 %2, %4, off offset:2048 sc0 sc1\n\t"
        "global_load_dwordx4 %3, %4, off offset:3072 sc0 sc1\n\t"
        "s_waitcnt vmcnt(0)"
        : "=&v"(t0), "=&v"(t1), "=&v"(t2), "=&v"(t3)
        : "v"(gp) : "memory");
    i32x4 tv[4] = {t0, t1, t2, t3};
#pragma unroll
    for (int k = 0; k < 4; ++k) {
        int row = 2 * w + (k >> 1);
        int g   = (k & 1) * 64 + lane;
        int idx = row * 128 + (g ^ (row & 7));
        *(i32x4*)(htile + idx * 8) = tv[k];
    }
}

__device__ __forceinline__ void wait_group(const int* __restrict__ gflags,
                                           int lane, int t) {
    for (;;) {
        int v = 0x7fffffff;
        if (lane < 8)
            v = __hip_atomic_load(&gflags[lane], __ATOMIC_RELAXED,
                                  __HIP_MEMORY_SCOPE_AGENT);
        if (__all(v >= t)) break;
        __builtin_amdgcn_s_sleep(1);
    }
    __atomic_signal_fence(__ATOMIC_SEQ_CST);  // compiler ordering only
}

#define MFMA_BF16 __builtin_amdgcn_mfma_f32_16x16x32_bf16

__global__ __launch_bounds__(512, 2) void rnn_kernel(
    const float* __restrict__ x,      // [B][T]
    const float* __restrict__ W_ih,   // [1+H][H]
    const float* __restrict__ b_ih,   // [H]
    const float* __restrict__ W_ho,   // [H][O]
    const float* __restrict__ b_ho,   // [O]
    float* __restrict__ out,          // [B][O]
    short* __restrict__ hbuf,         // ws: 2 * B * H bf16
    int*   __restrict__ flags)        // ws: [16][8] int (0xAA.. poison < 0)
{
    const int tid  = threadIdx.x;
    const int lane = tid & 63;
    const int w    = tid >> 6;      // wave 0..7
    const int cg   = w >> 2;        // col-group 0..1 (64 cols each)
    const int kq   = w & 3;         // k-quarter 0..3 (256 k each); owns m-tile kq
    const int q    = lane >> 4;
    const int n    = lane & 15;     // batch row (B/D col)

    const int i = blockIdx.x & 15;  // batch group
    const int j = blockIdx.x >> 4;  // member 0..7
    const int colbase = j * 128 + cg * 64;
    const int owncol  = colbase + kq * 16 + 4 * q;  // owner lane's 4 h cols
    const int row0    = i * 16;

    __shared__ float x_lds[16][Tn + 1];     // 32.8 KB
    __shared__ short htile[16 * Hn];        // 32 KB swizzled h slice
    __shared__ float redbuf[8 * 3 * 272];   // 26.1 KB partial-sum exchange

    // Stage x rows (coalesced fp32).
    for (int idx = tid; idx < 16 * Tn; idx += 512) {
        int r = idx >> 9, tt = idx & (Tn - 1);
        x_lds[r][tt] = x[(row0 + r) * Tn + tt];
    }

    // A = W^T frags: wave (cg,kq), tile mt: lane (q,n) holds
    // A[m=n][k=kq*256+ks*32+q*8+e] = W_ih[1+k][colbase+mt*16+n].
    bf16x8 wfrag[32];
#pragma unroll
    for (int mt = 0; mt < 4; ++mt)
#pragma unroll
        for (int ks = 0; ks < 8; ++ks) {
#pragma unroll
            for (int e = 0; e < 8; ++e) {
                int k = kq * 256 + ks * 32 + q * 8 + e;
                wfrag[mt * 8 + ks][e] =
                    f2bf(W_ih[(size_t)(1 + k) * Hn + colbase + mt * 16 + n]);
            }
        }
    const float4 bias4 = *(const float4*)(b_ih + owncol);
    const float4 w04   = *(const float4*)(W_ih + owncol);  // row 0 (x weight)

    __syncthreads();

    short* h0 = hbuf;
    short* h1 = hbuf + Bsz * Hn;
    int* myflags = flags + i * 8;
    const int swn   = n & 7;
    const int gbase = kq * 32;   // first 16B granule of this wave's k-quarter
    const f32x4 zero4 = {0.f, 0.f, 0.f, 0.f};

    for (int t = 0; t < Tn; ++t) {
        const float xv = x_lds[n][t];
        f32x4 aown = {bias4.x + xv * w04.x, bias4.y + xv * w04.y,
                      bias4.z + xv * w04.z, bias4.w + xv * w04.w};
        f32x4 hv;

        if (t > 0) {
            wait_group(myflags, lane, t);
            stage_h((t & 1) ? h1 : h0, htile, row0, w, lane);
            __syncthreads();

            f32x4 acc0 = (kq == 0) ? aown : zero4;
            f32x4 acc1 = (kq == 1) ? aown : zero4;
            f32x4 acc2 = (kq == 2) ? aown : zero4;
            f32x4 acc3 = (kq == 3) ? aown : zero4;
            const i32x4* lrow = (const i32x4*)(htile + n * Hn);
#pragma unroll
            for (int ks = 0; ks < 8; ++ks) {
                bf16x8 b = as_bf16x8(lrow[(gbase + ks * 4 + q) ^ swn]);
                acc0 = MFMA_BF16(wfrag[0 * 8 + ks], b, acc0, 0, 0, 0);
                acc1 = MFMA_BF16(wfrag[1 * 8 + ks], b, acc1, 0, 0, 0);
                acc2 = MFMA_BF16(wfrag[2 * 8 + ks], b, acc2, 0, 0, 0);
                acc3 = MFMA_BF16(wfrag[3 * 8 + ks], b, acc3, 0, 0, 0);
            }

            // Exchange k-partials: wave kq owns m-tile kq; writes the other 3.
#define WRITE_PART(MT, ACC)                                                  \
            if (kq != MT) {                                                  \
                int src = (kq < MT) ? kq : kq - 1;                           \
                float* bp = redbuf + ((cg * 4 + MT) * 3 + src) * 272 + n;    \
                bp[(4 * q + 0) * 17] = ACC[0];                               \
                bp[(4 * q + 1) * 17] = ACC[1];                               \
                bp[(4 * q + 2) * 17] = ACC[2];                               \
                bp[(4 * q + 3) * 17] = ACC[3];                               \
            }
            WRITE_PART(0, acc0)
            WRITE_PART(1, acc1)
            WRITE_PART(2, acc2)
            WRITE_PART(3, acc3)
#undef WRITE_PART
            __syncthreads();

            hv = (kq == 0) ? acc0 : (kq == 1) ? acc1 : (kq == 2) ? acc2 : acc3;
            const float* bp = redbuf + (cg * 4 + kq) * 3 * 272 + n;
#pragma unroll
            for (int src = 0; src < 3; ++src) {
#pragma unroll
                for (int r = 0; r < 4; ++r)
                    hv[r] += bp[src * 272 + (4 * q + r) * 17];
            }
        } else {
            hv = aown;
        }

        // h_{t+1}[row0+n][owncol .. owncol+3] = tanh(hv) — one 8B store.
        short s0 = f2bf(fast_tanh(hv[0]));
        short s1 = f2bf(fast_tanh(hv[1]));
        short s2 = f2bf(fast_tanh(hv[2]));
        short s3 = f2bf(fast_tanh(hv[3]));
        i32x2 pk;
        pk[0] = (s0 & 0xffff) | ((int)s1 << 16);
        pk[1] = (s2 & 0xffff) | ((int)s3 << 16);
        short* hdst = (((t + 1) & 1) ? h1 : h0) + (size_t)(row0 + n) * Hn + owncol;
        asm volatile("global_store_dwordx2 %0, %1, off sc0 sc1"
                     :: "v"(hdst), "v"(pk) : "memory");
        asm volatile("s_waitcnt vmcnt(0)" ::: "memory");  // drain to MALL
        __syncthreads();  // all waves drained; protects htile + redbuf reuse
        if (tid == 0)
            __hip_atomic_store(&flags[i * 8 + j], t + 1, __ATOMIC_RELAXED,
                               __HIP_MEMORY_SCOPE_AGENT);
    }

    // ---- Epilogue: out[16i..+16][32j..+32] = h_T @ W_ho + b_ho ----
    wait_group(myflags, lane, Tn);
    stage_h(h0, htile, row0, w, lane);   // h_T in buffer 0 (Tn even)
    __syncthreads();

    f32x4 e0 = zero4, e1 = zero4;        // nt = 0,1 (16 out-cols each)
    {
        const i32x4* lrow = (const i32x4*)(htile + n * Hn);
#pragma unroll
        for (int kk = 0; kk < 4; ++kk) {
            bf16x8 af = as_bf16x8(lrow[(w * 16 + kk * 4 + q) ^ swn]);
            bf16x8 b0, b1;
#pragma unroll
            for (int e = 0; e < 8; ++e) {
                const float* wp = W_ho +
                    (size_t)(w * 128 + kk * 32 + q * 8 + e) * On + j * 32 + n;
                b0[e] = f2bf(wp[0]);
                b1[e] = f2bf(wp[16]);
            }
            e0 = MFMA_BF16(af, b0, e0, 0, 0, 0);
            e1 = MFMA_BF16(af, b1, e1, 0, 0, 0);
        }
    }
    {   // redE[w][16][33]: D[m=4q+r][col=nt*16+n], m = batch row.
        float* re = redbuf + w * 528;
#pragma unroll
        for (int r = 0; r < 4; ++r) {
            re[(4 * q + r) * 33 + n]      = e0[r];
            re[(4 * q + r) * 33 + 16 + n] = e1[r];
        }
    }
    __syncthreads();
    {
        int r = tid >> 5, c = tid & 31;
        float s = b_ho[j * 32 + c];
#pragma unroll
        for (int w8 = 0; w8 < 8; ++w8)
            s += redbuf[w8 * 528 + r * 33 + c];
        out[(size_t)(row0 + r) * On + j * 32 + c] = s;
    }
}

extern "C" void kernel_launch(void* const* d_in, const int* in_sizes, int n_in,
                              void* d_out, int out_size, void* d_ws, size_t ws_size,
                              hipStream_t stream) {
    const float* x    = (const float*)d_in[0];
    const float* W_ih = (const float*)d_in[1];
    const float* b_ih = (const float*)d_in[2];
    const float* W_ho = (const float*)d_in[3];
    const float* b_ho = (const float*)d_in[4];
    float* out = (float*)d_out;

    size_t need = (size_t)2 * Bsz * Hn * sizeof(short) + 16 * 8 * sizeof(int);
    if (ws_size < need) return;

    short* hbuf  = (short*)d_ws;
    int*   flags = (int*)((char*)d_ws + (size_t)2 * Bsz * Hn * sizeof(short));

    rnn_kernel<<<128, 512, 0, stream>>>(x, W_ih, b_ih, W_ho, b_ho, out,
                                        hbuf, flags);
}

// Round 6
// 1117.213 us; speedup vs baseline: 1.4642x; 1.4642x over previous
//
#include <hip/hip_runtime.h>
#include <hip/hip_bf16.h>

// Elman RNN: B=256, T=512, H=1024, O=256 (fp32 in/out), MI355X gfx950.
// Round 6: flagless sync via parity-tagged fp16 h data.
// 128 WGs = 16 batch-groups x 8 members, 512 threads (2 col-groups x 4
// k-quarters). W_ih slice (1024x128) in registers as fp16 A-frags (A=W^T).
// h double-buffered fp16 in d_ws; every stored dword carries step-parity
// tag(s) = ((s+1)>>1)&1 in bit 0 (LSB of low fp16 elem; <=2^-10 error,
// still finer than bf16). Producers store write-through (sc0|sc1) and DO
// NOT drain; no flags. Consumers poll the data: issue staging loads, check
// all 16 dword tags, retry until fresh. Causality (visible store => its
// data-dependent prior loads serviced) preserves the <=2-step buffer skew.
// 2 barriers/step (htile ready, k-partial redbuf ready).

#define Bsz 256
#define Tn  512
#define Hn  1024
#define On  256

typedef __attribute__((ext_vector_type(8))) _Float16 f16x8;  // 4 VGPR
typedef __attribute__((ext_vector_type(4))) float f32x4;
typedef __attribute__((ext_vector_type(4))) int   i32x4;
typedef __attribute__((ext_vector_type(2))) int   i32x2;

__device__ __forceinline__ unsigned f2h(float f) {
    _Float16 h = (_Float16)f;
    union { _Float16 h; unsigned short s; } u; u.h = h;
    return (unsigned)u.s;
}

__device__ __forceinline__ f16x8 as_f16x8(i32x4 v) {
    union { i32x4 i; f16x8 h; } u; u.i = v; return u.h;
}

// tanh = (e^{2x}-1)/(e^{2x}+1); |err| ~1e-6 << fp16 rounding.
__device__ __forceinline__ float fast_tanh(float x) {
    float xc = fminf(fmaxf(x, -9.f), 9.f);
    float e  = __builtin_amdgcn_exp2f(xc * 2.8853900817779268f);
    return (e - 1.f) * __builtin_amdgcn_rcpf(e + 1.f);
}

// Poll-stage this group's 16x1024 fp16 h slice into LDS (wave w: rows
// 2w,2w+1). Each load instr = one contiguous 1024B span (8 full lines),
// sc0|sc1 bypass. Retry until every dword's bit0 == tag. LDS: granule g of
// row r at 16B-index r*128 + (g ^ (r&7)) (conflict-free permutation,
// matches MFMA B-frag read swizzle).
__device__ __forceinline__ void stage_h_poll(const short* __restrict__ hsrc,
                                             short* __restrict__ htile,
                                             int row0, int w, int lane,
                                             unsigned tag) {
    const short* gp = hsrc + (size_t)(row0 + 2 * w) * Hn + lane * 8;
    i32x4 t0, t1, t2, t3;
    for (;;) {
        asm volatile(
            "global_load_dwordx4 %0, %4, off sc0 sc1\n\t"
            "global_load_dwordx4 %1, %4, off offset:1024 sc0 sc1\n\t"
            "global_load_dwordx4 %2, %4, off offset:2048 sc0 sc1\n\t"
            "global_load_dwordx4 %3, %4, off offset:3072 sc0 sc1\n\t"
            "s_waitcnt vmcnt(0)"
            : "=&v"(t0), "=&v"(t1), "=&v"(t2), "=&v"(t3)
            : "v"(gp) : "memory");
        unsigned bad = 0;
#pragma unroll
        for (int e = 0; e < 4; ++e)
            bad |= (unsigned)(t0[e] ^ tag) | (unsigned)(t1[e] ^ tag) |
                   (unsigned)(t2[e] ^ tag) | (unsigned)(t3[e] ^ tag);
        if (!__any(bad & 1u)) break;
    }
    i32x4 tv[4] = {t0, t1, t2, t3};
#pragma unroll
    for (int k = 0; k < 4; ++k) {
        int row = 2 * w + (k >> 1);
        int g   = (k & 1) * 64 + lane;
        int idx = row * 128 + (g ^ (row & 7));
        *(i32x4*)(htile + idx * 8) = tv[k];
    }
}

#define MFMA_F16 __builtin_amdgcn_mfma_f32_16x16x32_f16

__global__ __launch_bounds__(512, 2) void rnn_kernel(
    const float* __restrict__ x,      // [B][T]
    const float* __restrict__ W_ih,   // [1+H][H]
    const float* __restrict__ b_ih,   // [H]
    const float* __restrict__ W_ho,   // [H][O]
    const float* __restrict__ b_ho,   // [O]
    float* __restrict__ out,          // [B][O]
    short* __restrict__ hbuf)         // ws: 2 * B * H fp16
{
    const int tid  = threadIdx.x;
    const int lane = tid & 63;
    const int w    = tid >> 6;      // wave 0..7
    const int cg   = w >> 2;        // col-group 0..1 (64 cols each)
    const int kq   = w & 3;         // k-quarter 0..3; owns m-tile kq
    const int q    = lane >> 4;
    const int n    = lane & 15;     // batch row (B/D col)

    const int i = blockIdx.x & 15;  // batch group
    const int j = blockIdx.x >> 4;  // member 0..7
    const int colbase = j * 128 + cg * 64;
    const int owncol  = colbase + kq * 16 + 4 * q;  // owner lane's 4 h cols
    const int row0    = i * 16;

    __shared__ float x_lds[16][Tn + 1];     // 32.8 KB
    __shared__ short htile[16 * Hn];        // 32 KB swizzled fp16 h slice
    __shared__ float redbuf[8 * 3 * 272];   // 26.1 KB partial-sum exchange

    // Stage x rows (coalesced fp32).
    for (int idx = tid; idx < 16 * Tn; idx += 512) {
        int r = idx >> 9, tt = idx & (Tn - 1);
        x_lds[r][tt] = x[(row0 + r) * Tn + tt];
    }

    // A = W^T frags (fp16): wave (cg,kq), tile mt: lane (q,n) holds
    // A[m=n][k=kq*256+ks*32+q*8+e] = W_ih[1+k][colbase+mt*16+n].
    f16x8 wfrag[32];
#pragma unroll
    for (int mt = 0; mt < 4; ++mt)
#pragma unroll
        for (int ks = 0; ks < 8; ++ks) {
#pragma unroll
            for (int e = 0; e < 8; ++e) {
                int k = kq * 256 + ks * 32 + q * 8 + e;
                wfrag[mt * 8 + ks][e] =
                    (_Float16)W_ih[(size_t)(1 + k) * Hn + colbase + mt * 16 + n];
            }
        }
    const float4 bias4 = *(const float4*)(b_ih + owncol);
    const float4 w04   = *(const float4*)(W_ih + owncol);  // row 0 (x weight)

    __syncthreads();

    short* h0 = hbuf;
    short* h1 = hbuf + Bsz * Hn;
    const int swn   = n & 7;
    const int gbase = kq * 32;
    const f32x4 zero4 = {0.f, 0.f, 0.f, 0.f};

    for (int t = 0; t < Tn; ++t) {
        const float xv = x_lds[n][t];
        f32x4 aown = {bias4.x + xv * w04.x, bias4.y + xv * w04.y,
                      bias4.z + xv * w04.z, bias4.w + xv * w04.w};
        f32x4 hv;

        if (t > 0) {
            // Consume h_t: buffer t&1, expected tag ((t+1)>>1)&1.
            stage_h_poll((t & 1) ? h1 : h0, htile, row0, w, lane,
                         (unsigned)((t + 1) >> 1) & 1u);
            __syncthreads();

            f32x4 acc0 = (kq == 0) ? aown : zero4;
            f32x4 acc1 = (kq == 1) ? aown : zero4;
            f32x4 acc2 = (kq == 2) ? aown : zero4;
            f32x4 acc3 = (kq == 3) ? aown : zero4;
            const i32x4* lrow = (const i32x4*)(htile + n * Hn);
#pragma unroll
            for (int ks = 0; ks < 8; ++ks) {
                f16x8 b = as_f16x8(lrow[(gbase + ks * 4 + q) ^ swn]);
                acc0 = MFMA_F16(wfrag[0 * 8 + ks], b, acc0, 0, 0, 0);
                acc1 = MFMA_F16(wfrag[1 * 8 + ks], b, acc1, 0, 0, 0);
                acc2 = MFMA_F16(wfrag[2 * 8 + ks], b, acc2, 0, 0, 0);
                acc3 = MFMA_F16(wfrag[3 * 8 + ks], b, acc3, 0, 0, 0);
            }

            // Exchange k-partials: wave kq owns m-tile kq; writes other 3.
#define WRITE_PART(MT, ACC)                                                  \
            if (kq != MT) {                                                  \
                int src = (kq < MT) ? kq : kq - 1;                           \
                float* bp = redbuf + ((cg * 4 + MT) * 3 + src) * 272 + n;    \
                bp[(4 * q + 0) * 17] = ACC[0];                               \
                bp[(4 * q + 1) * 17] = ACC[1];                               \
                bp[(4 * q + 2) * 17] = ACC[2];                               \
                bp[(4 * q + 3) * 17] = ACC[3];                               \
            }
            WRITE_PART(0, acc0)
            WRITE_PART(1, acc1)
            WRITE_PART(2, acc2)
            WRITE_PART(3, acc3)
#undef WRITE_PART
            __syncthreads();

            hv = (kq == 0) ? acc0 : (kq == 1) ? acc1 : (kq == 2) ? acc2 : acc3;
            const float* bp = redbuf + (cg * 4 + kq) * 3 * 272 + n;
#pragma unroll
            for (int src = 0; src < 3; ++src) {
#pragma unroll
                for (int r = 0; r < 4; ++r)
                    hv[r] += bp[src * 272 + (4 * q + r) * 17];
            }
        } else {
            hv = aown;
        }

        // Store h_{t+1}: buffer (t+1)&1, every dword tagged in bit 0 with
        // tag(t+1) = ((t+2)>>1)&1. Fire-and-forget (no drain, no flag).
        unsigned tagn = (unsigned)((t + 2) >> 1) & 1u;
        unsigned e0 = f2h(fast_tanh(hv[0])), e1 = f2h(fast_tanh(hv[1]));
        unsigned e2 = f2h(fast_tanh(hv[2])), e3 = f2h(fast_tanh(hv[3]));
        i32x2 pk;
        pk[0] = (int)(((e0 & ~1u) | tagn) | (e1 << 16));
        pk[1] = (int)(((e2 & ~1u) | tagn) | (e3 << 16));
        short* hdst = (((t + 1) & 1) ? h1 : h0) + (size_t)(row0 + n) * Hn + owncol;
        asm volatile("global_store_dwordx2 %0, %1, off sc0 sc1"
                     :: "v"(hdst), "v"(pk) : "memory");
    }

    // ---- Epilogue: out[16i..+16][32j..+32] = h_T @ W_ho + b_ho ----
    // h_512 in buffer 0, tag ((512+1)>>1)&1 = 0 (prev content h_510 tag 1).
    stage_h_poll(h0, htile, row0, w, lane, 0u);
    __syncthreads();

    f32x4 e0 = zero4, e1 = zero4;        // nt = 0,1 (16 out-cols each)
    {
        const i32x4* lrow = (const i32x4*)(htile + n * Hn);
#pragma unroll
        for (int kk = 0; kk < 4; ++kk) {
            f16x8 af = as_f16x8(lrow[(w * 16 + kk * 4 + q) ^ swn]);
            f16x8 b0, b1;
#pragma unroll
            for (int e = 0; e < 8; ++e) {
                const float* wp = W_ho +
                    (size_t)(w * 128 + kk * 32 + q * 8 + e) * On + j * 32 + n;
                b0[e] = (_Float16)wp[0];
                b1[e] = (_Float16)wp[16];
            }
            e0 = MFMA_F16(af, b0, e0, 0, 0, 0);
            e1 = MFMA_F16(af, b1, e1, 0, 0, 0);
        }
    }
    {   // redE[w][16][33]: D[m=4q+r][col=nt*16+n], m = batch row.
        float* re = redbuf + w * 528;
#pragma unroll
        for (int r = 0; r < 4; ++r) {
            re[(4 * q + r) * 33 + n]      = e0[r];
            re[(4 * q + r) * 33 + 16 + n] = e1[r];
        }
    }
    __syncthreads();
    {
        int r = tid >> 5, c = tid & 31;
        float s = b_ho[j * 32 + c];
#pragma unroll
        for (int w8 = 0; w8 < 8; ++w8)
            s += redbuf[w8 * 528 + r * 33 + c];
        out[(size_t)(row0 + r) * On + j * 32 + c] = s;
    }
}

extern "C" void kernel_launch(void* const* d_in, const int* in_sizes, int n_in,
                              void* d_out, int out_size, void* d_ws, size_t ws_size,
                              hipStream_t stream) {
    const float* x    = (const float*)d_in[0];
    const float* W_ih = (const float*)d_in[1];
    const float* b_ih = (const float*)d_in[2];
    const float* W_ho = (const float*)d_in[3];
    const float* b_ho = (const float*)d_in[4];
    float* out = (float*)d_out;

    size_t need = (size_t)2 * Bsz * Hn * sizeof(short);
    if (ws_size < need) return;

    short* hbuf = (short*)d_ws;

    rnn_kernel<<<128, 512, 0, stream>>>(x, W_ih, b_ih, W_ho, b_ho, out, hbuf);
}

// Round 7
// 1081.558 us; speedup vs baseline: 1.5124x; 1.0330x over previous
//
#include <hip/hip_runtime.h>
#include <hip/hip_bf16.h>

// Elman RNN: B=256, T=512, H=1024, O=256 (fp32 in/out), MI355X gfx950.
// Round 7: quarter-granular arrival consumption.
// 128 WGs = 16 batch-groups x 8 members, 512 threads (2 col-groups x 4
// k-quarters). W_ih slice (1024x128) in registers as fp16 A-frags (A=W^T).
// h double-buffered fp16 in d_ws; dwords carry step-parity tag in bit 0.
// Wave (cg,kq) stages ONLY region kq (256 cols = members 2kq,2kq+1), rows
// cg*8..+7, and starts its MFMAs after a pairwise LDS sync with its region
// partner — early quarters compute while late quarters are still arriving.
// One WG barrier per step (k-partial exchange, b128 conflict-free, double
// buffered). Fire-and-forget sc0|sc1 write-through stores; no flags/fences.

#define Bsz 256
#define Tn  512
#define Hn  1024
#define On  256

typedef __attribute__((ext_vector_type(8))) _Float16 f16x8;  // 4 VGPR
typedef __attribute__((ext_vector_type(4))) float f32x4;
typedef __attribute__((ext_vector_type(4))) int   i32x4;
typedef __attribute__((ext_vector_type(2))) int   i32x2;

__device__ __forceinline__ unsigned f2h(float f) {
    _Float16 h = (_Float16)f;
    union { _Float16 h; unsigned short s; } u; u.h = h;
    return (unsigned)u.s;
}

__device__ __forceinline__ f16x8 as_f16x8(i32x4 v) {
    union { i32x4 i; f16x8 h; } u; u.i = v; return u.h;
}

// tanh = (e^{2x}-1)/(e^{2x}+1); |err| ~1e-6 << fp16 rounding.
__device__ __forceinline__ float fast_tanh(float x) {
    float xc = fminf(fmaxf(x, -9.f), 9.f);
    float e  = __builtin_amdgcn_exp2f(xc * 2.8853900817779268f);
    return (e - 1.f) * __builtin_amdgcn_rcpf(e + 1.f);
}

#define MFMA_F16 __builtin_amdgcn_mfma_f32_16x16x32_f16

// Poll-stage region kq (cols kq*256..+255), rows r0..r0+7 of this group's
// h slice into swizzled LDS. Each load instr: lanes 0-31 row r, lanes
// 32-63 row r+1, 512B contiguous per row (4 full lines each). Retries
// wait only on members 2kq/2kq+1's tagged data.
__device__ __forceinline__ void stage_quarter(const short* __restrict__ hsrc,
                                              short* __restrict__ htile,
                                              int row0, int cg, int kq,
                                              int lane, unsigned tag) {
    const int half = lane >> 5, gl = lane & 31, r0 = cg * 8;
    const short* a0 = hsrc + (size_t)(row0 + r0 + 0 + half) * Hn + kq * 256 + gl * 8;
    const short* a1 = hsrc + (size_t)(row0 + r0 + 2 + half) * Hn + kq * 256 + gl * 8;
    const short* a2 = hsrc + (size_t)(row0 + r0 + 4 + half) * Hn + kq * 256 + gl * 8;
    const short* a3 = hsrc + (size_t)(row0 + r0 + 6 + half) * Hn + kq * 256 + gl * 8;
    i32x4 t0, t1, t2, t3;
    for (;;) {
        asm volatile("global_load_dwordx4 %0, %1, off sc0 sc1"
                     : "=&v"(t0) : "v"(a0) : "memory");
        asm volatile("global_load_dwordx4 %0, %1, off sc0 sc1"
                     : "=&v"(t1) : "v"(a1) : "memory");
        asm volatile("global_load_dwordx4 %0, %1, off sc0 sc1"
                     : "=&v"(t2) : "v"(a2) : "memory");
        asm volatile("global_load_dwordx4 %0, %1, off sc0 sc1"
                     : "=&v"(t3) : "v"(a3) : "memory");
        asm volatile("s_waitcnt vmcnt(0)" ::: "memory");
        unsigned bad = 0;
#pragma unroll
        for (int e = 0; e < 4; ++e)
            bad |= (unsigned)(t0[e] ^ tag) | (unsigned)(t1[e] ^ tag) |
                   (unsigned)(t2[e] ^ tag) | (unsigned)(t3[e] ^ tag);
        if (!__any(bad & 1u)) break;
    }
    i32x4 tv[4] = {t0, t1, t2, t3};
#pragma unroll
    for (int p = 0; p < 4; ++p) {
        int row = r0 + 2 * p + half;
        int g   = kq * 32 + gl;
        int idx = row * 128 + (g ^ (row & 7));
        *(i32x4*)(htile + idx * 8) = tv[p];
    }
}

__global__ __launch_bounds__(512, 2) void rnn_kernel(
    const float* __restrict__ x,      // [B][T]
    const float* __restrict__ W_ih,   // [1+H][H]
    const float* __restrict__ b_ih,   // [H]
    const float* __restrict__ W_ho,   // [H][O]
    const float* __restrict__ b_ho,   // [O]
    float* __restrict__ out,          // [B][O]
    short* __restrict__ hbuf)         // ws: 2 * B * H fp16
{
    const int tid  = threadIdx.x;
    const int lane = tid & 63;
    const int w    = tid >> 6;      // wave 0..7
    const int cg   = w >> 2;        // col-group 0..1 (64 cols each)
    const int kq   = w & 3;         // k-quarter 0..3; owns m-tile kq of its cg
    const int q    = lane >> 4;
    const int n    = lane & 15;     // batch row (B/D col)

    const int i = blockIdx.x & 15;  // batch group
    const int j = blockIdx.x >> 4;  // member 0..7
    const int colbase = j * 128 + cg * 64;
    const int owncol  = colbase + kq * 16 + 4 * q;  // owner lane's 4 h cols
    const int row0    = i * 16;

    __shared__ float x_lds[16][Tn + 1];     // 32.8 KB
    __shared__ short htile[16 * Hn];        // 32 KB swizzled fp16 h slice
    __shared__ float redbuf[2][8 * 3 * 256];// 48 KB b128 partial exchange
    __shared__ int   pairflag[4];           // region-pair arrival counters

    if (tid < 4) pairflag[tid] = 0;

    // Stage x rows (coalesced fp32).
    for (int idx = tid; idx < 16 * Tn; idx += 512) {
        int r = idx >> 9, tt = idx & (Tn - 1);
        x_lds[r][tt] = x[(row0 + r) * Tn + tt];
    }

    // A = W^T frags (fp16): wave (cg,kq), tile mt: lane (q,n) holds
    // A[m=n][k=kq*256+ks*32+q*8+e] = W_ih[1+k][colbase+mt*16+n].
    f16x8 wfrag[32];
#pragma unroll
    for (int mt = 0; mt < 4; ++mt)
#pragma unroll
        for (int ks = 0; ks < 8; ++ks) {
#pragma unroll
            for (int e = 0; e < 8; ++e) {
                int k = kq * 256 + ks * 32 + q * 8 + e;
                wfrag[mt * 8 + ks][e] =
                    (_Float16)W_ih[(size_t)(1 + k) * Hn + colbase + mt * 16 + n];
            }
        }
    const float4 bias4 = *(const float4*)(b_ih + owncol);
    const float4 w04   = *(const float4*)(W_ih + owncol);  // row 0 (x weight)

    __syncthreads();

    short* h0 = hbuf;
    short* h1 = hbuf + Bsz * Hn;
    const int swn   = n & 7;
    const int gbase = kq * 32;
    const int slot  = (q * 16 + n) * 4;   // lane's 16B slot in a redbuf plane
    const f32x4 zero4 = {0.f, 0.f, 0.f, 0.f};

    for (int t = 0; t < Tn; ++t) {
        const float xv = x_lds[n][t];
        f32x4 aown = {bias4.x + xv * w04.x, bias4.y + xv * w04.y,
                      bias4.z + xv * w04.z, bias4.w + xv * w04.w};
        f32x4 hv;

        if (t > 0) {
            // Poll + stage ONLY region kq (our 2 source members).
            stage_quarter((t & 1) ? h1 : h0, htile, row0, cg, kq, lane,
                          (unsigned)((t + 1) >> 1) & 1u);
            // Pairwise sync with region partner (other cg, same kq).
            asm volatile("s_waitcnt lgkmcnt(0)" ::: "memory");
            if (lane == 0)
                __hip_atomic_fetch_add(&pairflag[kq], 1, __ATOMIC_RELAXED,
                                       __HIP_MEMORY_SCOPE_WORKGROUP);
            while (__hip_atomic_load(&pairflag[kq], __ATOMIC_RELAXED,
                                     __HIP_MEMORY_SCOPE_WORKGROUP) < 2 * t) {}
            asm volatile("" ::: "memory");

            f32x4 acc0 = (kq == 0) ? aown : zero4;
            f32x4 acc1 = (kq == 1) ? aown : zero4;
            f32x4 acc2 = (kq == 2) ? aown : zero4;
            f32x4 acc3 = (kq == 3) ? aown : zero4;
            const i32x4* lrow = (const i32x4*)(htile + n * Hn);
#pragma unroll
            for (int ks = 0; ks < 8; ++ks) {
                f16x8 b = as_f16x8(lrow[(gbase + ks * 4 + q) ^ swn]);
                acc0 = MFMA_F16(wfrag[0 * 8 + ks], b, acc0, 0, 0, 0);
                acc1 = MFMA_F16(wfrag[1 * 8 + ks], b, acc1, 0, 0, 0);
                acc2 = MFMA_F16(wfrag[2 * 8 + ks], b, acc2, 0, 0, 0);
                acc3 = MFMA_F16(wfrag[3 * 8 + ks], b, acc3, 0, 0, 0);
            }

            // Exchange k-partials, b128 conflict-free, double-buffered.
            float* rb = redbuf[t & 1];
#define WRITE_PART(MT, ACC)                                                  \
            if (kq != MT) {                                                  \
                int src = (kq < MT) ? kq : kq - 1;                           \
                *(f32x4*)(rb + ((cg * 4 + MT) * 3 + src) * 256 + slot) = ACC;\
            }
            WRITE_PART(0, acc0)
            WRITE_PART(1, acc1)
            WRITE_PART(2, acc2)
            WRITE_PART(3, acc3)
#undef WRITE_PART
            __syncthreads();

            hv = (kq == 0) ? acc0 : (kq == 1) ? acc1 : (kq == 2) ? acc2 : acc3;
            const float* bp = rb + (cg * 4 + kq) * 3 * 256 + slot;
            f32x4 p0 = *(const f32x4*)(bp);
            f32x4 p1 = *(const f32x4*)(bp + 256);
            f32x4 p2 = *(const f32x4*)(bp + 512);
            hv = hv + p0 + p1 + p2;
        } else {
            hv = aown;
        }

        // Store h_{t+1}: buffer (t+1)&1, tag(t+1)=((t+2)>>1)&1 in bit 0 of
        // every dword. Fire-and-forget write-through.
        unsigned tagn = (unsigned)((t + 2) >> 1) & 1u;
        unsigned e0 = f2h(fast_tanh(hv[0])), e1 = f2h(fast_tanh(hv[1]));
        unsigned e2 = f2h(fast_tanh(hv[2])), e3 = f2h(fast_tanh(hv[3]));
        i32x2 pk;
        pk[0] = (int)(((e0 & ~1u) | tagn) | (e1 << 16));
        pk[1] = (int)(((e2 & ~1u) | tagn) | (e3 << 16));
        short* hdst = (((t + 1) & 1) ? h1 : h0) + (size_t)(row0 + n) * Hn + owncol;
        asm volatile("global_store_dwordx2 %0, %1, off sc0 sc1"
                     :: "v"(hdst), "v"(pk) : "memory");
    }

    // ---- Epilogue: out[16i..+16][32j..+32] = h_T @ W_ho + b_ho ----
    // h_512 in buffer 0, tag 0. All quarters staged, then full barrier.
    stage_quarter(h0, htile, row0, cg, kq, lane, 0u);
    __syncthreads();

    f32x4 e0 = zero4, e1 = zero4;        // nt = 0,1 (16 out-cols each)
    {
        const i32x4* lrow = (const i32x4*)(htile + n * Hn);
#pragma unroll
        for (int kk = 0; kk < 4; ++kk) {
            f16x8 af = as_f16x8(lrow[(w * 16 + kk * 4 + q) ^ swn]);
            f16x8 b0, b1;
#pragma unroll
            for (int e = 0; e < 8; ++e) {
                const float* wp = W_ho +
                    (size_t)(w * 128 + kk * 32 + q * 8 + e) * On + j * 32 + n;
                b0[e] = (_Float16)wp[0];
                b1[e] = (_Float16)wp[16];
            }
            e0 = MFMA_F16(af, b0, e0, 0, 0, 0);
            e1 = MFMA_F16(af, b1, e1, 0, 0, 0);
        }
    }
    {   // scratch in redbuf[0]: [w][16 rows][33]: D[m=4q+r][col=nt*16+n].
        float* re = redbuf[0] + w * 528;
#pragma unroll
        for (int r = 0; r < 4; ++r) {
            re[(4 * q + r) * 33 + n]      = e0[r];
            re[(4 * q + r) * 33 + 16 + n] = e1[r];
        }
    }
    __syncthreads();
    {
        int r = tid >> 5, c = tid & 31;
        float s = b_ho[j * 32 + c];
#pragma unroll
        for (int w8 = 0; w8 < 8; ++w8)
            s += redbuf[0][w8 * 528 + r * 33 + c];
        out[(size_t)(row0 + r) * On + j * 32 + c] = s;
    }
}

extern "C" void kernel_launch(void* const* d_in, const int* in_sizes, int n_in,
                              void* d_out, int out_size, void* d_ws, size_t ws_size,
                              hipStream_t stream) {
    const float* x    = (const float*)d_in[0];
    const float* W_ih = (const float*)d_in[1];
    const float* b_ih = (const float*)d_in[2];
    const float* W_ho = (const float*)d_in[3];
    const float* b_ho = (const float*)d_in[4];
    float* out = (float*)d_out;

    size_t need = (size_t)2 * Bsz * Hn * sizeof(short);
    if (ws_size < need) return;

    short* hbuf = (short*)d_ws;

    rnn_kernel<<<128, 512, 0, stream>>>(x, W_ih, b_ih, W_ho, b_ho, out, hbuf);
}